// Round 1
// baseline (195.059 us; speedup 1.0000x reference)
//
#include <hip/hip_runtime.h>
#include <stdint.h>

#define F 256
#define R 64                    // rows per block
#define THREADS 256
#define GCH 32                  // g-rows per W chunk
#define NCH (F / GCH)           // 8 chunks
#define CH_SLOTS (GCH * F / 8)  // 1024 16B slots per chunk

typedef __attribute__((ext_vector_type(8))) short short8;
typedef __attribute__((ext_vector_type(4))) float floatx4;

// Forced single-instruction rotate: alignbit(x,x,32-d) == rotl(x,d).
__device__ __forceinline__ uint32_t rotl32(uint32_t x, int d) {
  return __builtin_amdgcn_alignbit(x, x, (uint32_t)(32 - d));
}

// Threefry keys + hoisted round-injection constants (loop-invariant per thread:
// saves one literal-add per injection across all 64 feature evaluations).
struct TFK { uint32_t k0, k1, k2, a1, a2, a3, a4, a5; };

__device__ __forceinline__ TFK mkkeys(uint32_t k0, uint32_t k1) {
  TFK K;
  K.k0 = k0; K.k1 = k1; K.k2 = k0 ^ k1 ^ 0x1BD11BDAu;
  K.a1 = K.k2 + 1u; K.a2 = k0 + 2u; K.a3 = k1 + 3u;
  K.a4 = K.k2 + 4u; K.a5 = k0 + 5u;
  return K;
}

// Single-chain threefry2x32 (20 rounds) — used once per row for fold_in.
__device__ __forceinline__ void tf_one(const TFK& K, uint32_t& x0, uint32_t& x1) {
  x0 += K.k0; x1 += K.k1;
#define TF1(r) x0 += x1; x1 = rotl32(x1, r); x1 ^= x0;
  TF1(13) TF1(15) TF1(26) TF1(6)   x0 += K.k1; x1 += K.a1;
  TF1(17) TF1(29) TF1(16) TF1(24)  x0 += K.k2; x1 += K.a2;
  TF1(13) TF1(15) TF1(26) TF1(6)   x0 += K.k0; x1 += K.a3;
  TF1(17) TF1(29) TF1(16) TF1(24)  x0 += K.k1; x1 += K.a4;
  TF1(13) TF1(15) TF1(26) TF1(6)   x0 += K.k2; x1 += K.a5;
#undef TF1
}

// Dual-chain threefry: counters i and i+1 advanced in manually interleaved
// lockstep — guarantees >=2-chain ILP per call (dep latency 4cyc vs 2cyc
// issue means a lone chain caps VALU at 50%).
__device__ __forceinline__ void tf_pair(const TFK& K, uint32_t i,
                                        uint32_t& oa, uint32_t& ob) {
  uint32_t a0 = K.k0, a1 = K.k1 + i;        // x0 = 0+k0, x1 = i+k1
  uint32_t b0 = K.k0, b1 = K.k1 + i + 1u;
#define TF2(r)  a0 += a1; b0 += b1;                         \
                a1 = rotl32(a1, r); b1 = rotl32(b1, r);     \
                a1 ^= a0; b1 ^= b0;
#define INJ2(u, v) a0 += (u); b0 += (u); a1 += (v); b1 += (v);
  TF2(13) TF2(15) TF2(26) TF2(6)   INJ2(K.k1, K.a1)
  TF2(17) TF2(29) TF2(16) TF2(24)  INJ2(K.k2, K.a2)
  TF2(13) TF2(15) TF2(26) TF2(6)   INJ2(K.k0, K.a3)
  TF2(17) TF2(29) TF2(16) TF2(24)  INJ2(K.k1, K.a4)
  TF2(13) TF2(15) TF2(26) TF2(6)   INJ2(K.k2, K.a5)
#undef TF2
#undef INJ2
  oa = a0 ^ a1;
  ob = b0 ^ b1;
}

// Two partitionable-threefry features (counters i, i+1) -> packed bf16 pair.
// Bit-identical to the verified kernel: same 100*2^-32 scale (do NOT multiply
// by 100 again), same RNE-to-bf16, v_perm pack == (ulo>>16)|((uhi>>16)<<16).
__device__ __forceinline__ uint32_t featpack(const TFK& K, uint32_t i) {
  uint32_t xa, xb;
  tf_pair(K, i, xa, xb);
  uint32_t ulo = __float_as_uint((float)xa * 2.3283064365386963e-8f);
  uint32_t uhi = __float_as_uint((float)xb * 2.3283064365386963e-8f);
  ulo += 0x7FFFu + ((ulo >> 16) & 1u);
  uhi += 0x7FFFu + ((uhi >> 16) & 1u);
  return __builtin_amdgcn_perm(uhi, ulo, 0x07060302u);
}

// fp32 -> bf16 RNE (conv kernel only)
__device__ __forceinline__ uint32_t f2bf(float f) {
  uint32_t u = __float_as_uint(f);
  u += 0x7FFFu + ((u >> 16) & 1u);
  return u >> 16;
}

// One-time: W fp32 -> bf16 TRANSPOSED into slot order (unchanged).
// Slot s: chunk gt=s>>10, c=(s>>5)&31 (k-granule), g=s&31.
// Holds W[gt*32+g][c*8 .. c*8+7] as 8 bf16.
__global__ __launch_bounds__(256) void femb_conv(const float* __restrict__ W,
                                                 uint16_t* __restrict__ ws) {
  int s = blockIdx.x * 256 + threadIdx.x;   // 8192 slots
  int gt = s >> 10;
  int c = (s >> 5) & 31;
  int g = s & 31;
  const float4* src = (const float4*)(W + (size_t)(gt * GCH + g) * F + c * 8);
  float4 v0 = src[0], v1 = src[1];
  short8 o;
  o[0] = (short)f2bf(v0.x); o[1] = (short)f2bf(v0.y);
  o[2] = (short)f2bf(v0.z); o[3] = (short)f2bf(v0.w);
  o[4] = (short)f2bf(v1.x); o[5] = (short)f2bf(v1.y);
  o[6] = (short)f2bf(v1.z); o[7] = (short)f2bf(v1.w);
  *(short8*)(ws + (size_t)s * 8) = o;
}

// No-LDS version: W chunk is 16 KB and fully L1/L2-resident after the first
// blocks touch it — staging it through LDS bought nothing and cost 8 barriers
// (each a vmcnt(0) drain ganging all 4 waves) + 32 KB LDS of occupancy.
// B-fragments now come straight from global in the same slot order.
__global__ __launch_bounds__(THREADS, 4) void femb_main(
    const float* __restrict__ x, const uint16_t* __restrict__ Wbf,
    const float* __restrict__ bias, float* __restrict__ out) {
  const int tid  = threadIdx.x;
  const int lane = tid & 63;
  const int wave = tid >> 6;
  const int qd   = lane >> 4;
  const int l16  = lane & 15;
  const size_t row0 = (size_t)blockIdx.x * R;
  const int myrow = (int)row0 + wave * 16 + l16;

  float xv = x[myrow];

  // fold_in: key = threefry((0,42), (0, bitcast(x))). 4x redundant across qd.
  TFK K42 = mkkeys(0u, 42u);
  uint32_t s0 = 0u, s1 = __float_as_uint(xv);
  tf_one(K42, s0, s1);
  const TFK K = mkkeys(s0, s1);

  // RNG straight into A-fragments: lane (qd,l16) of wave w owns
  // A[m=l16][k=qd*8+j] for row w*16+l16 -> features kt*32+qd*8+j.
  short8 afrag[8];
  #pragma unroll
  for (int kt = 0; kt < 8; ++kt) {
    const uint32_t fb = (uint32_t)(kt * 32 + qd * 8);
    uint32_t w32[4];
    #pragma unroll
    for (int p = 0; p < 4; ++p)
      w32[p] = featpack(K, fb + 2 * p);
    union { uint32_t w[4]; short8 s; } u;
    u.w[0] = w32[0]; u.w[1] = w32[1]; u.w[2] = w32[2]; u.w[3] = w32[3];
    afrag[kt] = u.s;
  }

  // Chunk loop, barrier-free. unroll 1: keeps straight-line code (and I$
  // footprint) dominated by the RNG section; wave-level overlap covers the
  // per-iteration L1/L2 load latency.
  #pragma unroll 1
  for (int gt = 0; gt < NCH; ++gt) {
    const uint16_t* Wc = Wbf + (size_t)gt * CH_SLOTS * 8;
    floatx4 acc[2];
    acc[0] = (floatx4){0.f, 0.f, 0.f, 0.f};
    acc[1] = (floatx4){0.f, 0.f, 0.f, 0.f};
    #pragma unroll
    for (int kt = 0; kt < 8; ++kt) {
      int c = kt * 4 + qd;
      #pragma unroll
      for (int n = 0; n < 2; ++n) {
        // slot = c*32 + n*16 + l16: 16 consecutive b128 per 16-lane group
        // -> global_load_dwordx4, 4x 256B segments per wave-instr, L1-hot.
        short8 b = *(const short8*)(Wc + (size_t)(c * 32 + n * 16 + l16) * 8);
        acc[n] = __builtin_amdgcn_mfma_f32_16x16x32_bf16(afrag[kt], b, acc[n], 0, 0, 0);
      }
    }

    // Epilogue: D[row=qd*4+reg][col=l16] (m89-verified layout). Unchanged.
    #pragma unroll
    for (int n = 0; n < 2; ++n) {
      int g = gt * GCH + n * 16 + l16;
      float bg = bias[g];
      #pragma unroll
      for (int reg = 0; reg < 4; ++reg) {
        size_t grow = row0 + (size_t)wave * 16 + qd * 4 + reg;
        out[grow * F + g] = acc[n][reg] + bg;
      }
    }
  }
}

extern "C" void kernel_launch(void* const* d_in, const int* in_sizes, int n_in,
                              void* d_out, int out_size, void* d_ws, size_t ws_size,
                              hipStream_t stream) {
  const float* x = (const float*)d_in[0];
  const float* W = (const float*)d_in[1];
  const float* b = (const float*)d_in[2];
  float* out = (float*)d_out;
  uint16_t* wsbf = (uint16_t*)d_ws;          // 128 KB of ws_size
  const int nrows = in_sizes[0];             // 131072
  const int blocks = nrows / R;              // 2048

  hipLaunchKernelGGL(femb_conv, dim3((F * F / 8) / 256), dim3(256), 0, stream, W, wsbf);
  hipLaunchKernelGGL(femb_main, dim3(blocks), dim3(THREADS), 0, stream,
                     x, wsbf, b, out);
}